// Round 5
// baseline (6265.481 us; speedup 1.0000x reference)
//
#include <hip/hip_runtime.h>

#define SEQ   512
#define BATCH 64
#define DIM   512

typedef float  f32x4 __attribute__((ext_vector_type(4)));
typedef short  s16x8 __attribute__((ext_vector_type(8)));
typedef __bf16 bf16x2 __attribute__((ext_vector_type(2)));

__device__ __forceinline__ float bits2f(unsigned u) {
  union { unsigned u; float f; } v; v.u = u; return v.f;
}
__device__ __forceinline__ float bf2f(unsigned short h) { return bits2f((unsigned)h << 16); }
__device__ __forceinline__ float bflo(unsigned u) { return bits2f(u << 16); }
__device__ __forceinline__ float bfhi(unsigned u) { return bits2f(u & 0xFFFF0000u); }
__device__ __forceinline__ unsigned short f2bf(float f) {
  union { float f; unsigned u; } v; v.f = f;
  unsigned r = v.u + 0x7FFFu + ((v.u >> 16) & 1u);
  return (unsigned short)(r >> 16);
}
__device__ __forceinline__ unsigned packbf(float lo, float hi) {
  return (unsigned)f2bf(lo) | ((unsigned)f2bf(hi) << 16);
}
__device__ __forceinline__ float sigm(float x) { return 1.0f / (1.0f + __expf(-x)); }

__device__ __forceinline__ float dot2(unsigned w, unsigned h, float acc) {
#if __has_builtin(__builtin_amdgcn_fdot2_f32_bf16)
  return __builtin_amdgcn_fdot2_f32_bf16(__builtin_bit_cast(bf16x2, w),
                                         __builtin_bit_cast(bf16x2, h), acc, false);
#else
  return acc + bflo(w) * bflo(h) + bfhi(w) * bfhi(h);
#endif
}

// Barrier draining ONLY LDS (lgkmcnt) — global prefetch loads / out-stores stay
// in flight. Safe: no intra-kernel global RAW (prev-trajectory cols are written
// only by EARLIER kernel launches).
__device__ __forceinline__ void bar_lds() {
  asm volatile("s_waitcnt lgkmcnt(0)\n\ts_barrier" ::: "memory");
}

template<int N>
__device__ __forceinline__ void pinv(unsigned (&w)[N]) {
#pragma unroll
  for (int k = 0; k < N; ++k) asm volatile("" : "+v"(w[k]));
}

// ---------------------------------------------------------------------------
// Kernel 1: cast/pack weights (validated R2-R4).
// ---------------------------------------------------------------------------
#define NJOBS 18
struct CastJobs {
  const float* src[NJOBS];
  const float* src2[NJOBS];
  void*        dst[NJOBS];
  int          n[NJOBS];
  int          mode[NJOBS];
  int          m[NJOBS];
  int          iN[NJOBS];
};

__global__ __launch_bounds__(256) void cast_kernel(CastJobs jobs) {
  int gsz = gridDim.x * blockDim.x;
  int gid = blockIdx.x * blockDim.x + threadIdx.x;
  for (int j = 0; j < NJOBS; ++j) {
    int n = jobs.n[j], mode = jobs.mode[j];
    int m = jobs.m[j], iN = jobs.iN[j];
    const float* s = jobs.src[j];
    if (mode == 1) {
      unsigned short* d = (unsigned short*)jobs.dst[j];
      for (int i = gid; i < n; i += gsz) {
        int k = i >> 9, nn = i & 511;
        d[nn * 512 + k] = f2bf(s[i]);
      }
    } else if (mode == 3) {
      unsigned* d = (unsigned*)jobs.dst[j];
      for (int i = gid; i < n; i += gsz) {
        int k2 = i / m, jj = i - k2 * m;
        d[i] = packbf(s[(iN + 2 * k2) * m + jj], s[(iN + 2 * k2 + 1) * m + jj]);
      }
    } else if (mode == 4) {
      unsigned* d = (unsigned*)jobs.dst[j];
      for (int i = gid; i < n; i += gsz) {
        int k2 = i >> 7, jj = i & 127;
        d[i] = packbf(s[(2 * k2) * 128 + jj], s[(2 * k2 + 1) * 128 + jj]);
      }
    } else if (mode == 5) {
      unsigned* d = (unsigned*)jobs.dst[j];
      for (int i = gid; i < n; i += gsz) {
        int k2 = i >> 7, jj = i & 127;
        d[i] = packbf(s[(iN + 2 * k2) * 128 + jj], s[(iN + 2 * k2 + 1) * 128 + jj]);
      }
    } else if (mode == 6) {
      const float* s2 = jobs.src2[j];
      unsigned short* d = (unsigned short*)jobs.dst[j];
      for (int i = gid; i < n; i += gsz) {
        int nrow = i / iN, k = i - nrow * iN;
        float v = (nrow < m) ? s[k * m + nrow] : s2[k * 128 + (nrow - m)];
        d[i] = f2bf(v);
      }
    }
  }
}

// ---------------------------------------------------------------------------
// Kernel 2: projection GEMM (bf16 MFMA) — validated, unchanged.
// ---------------------------------------------------------------------------
__global__ __launch_bounds__(256) void proj_kernel(
    const float* __restrict__ x,
    const unsigned short* __restrict__ WbT,
    const float* __restrict__ bias0, const float* __restrict__ bias1,
    const float* __restrict__ bias2,
    unsigned short* __restrict__ p0, unsigned short* __restrict__ p1,
    unsigned short* __restrict__ p2)
{
  __shared__ __align__(16) unsigned short aS[64 * 40];
  __shared__ __align__(16) unsigned short bS[128 * 40];

  int bx = blockIdx.x;
  int nt = bx % 12, t = bx / 12;
  int wsel = nt >> 2, ncol0 = (nt & 3) * 128;
  const float* bias = (wsel == 0) ? bias0 : (wsel == 1 ? bias1 : bias2);
  unsigned short* pout = (wsel == 0) ? p0 : (wsel == 1 ? p1 : p2);

  int tid = threadIdx.x;
  int wv = tid >> 6, lane = tid & 63;
  int lq = lane & 15, quad = lane >> 4;

  f32x4 acc[8];
#pragma unroll
  for (int s = 0; s < 8; ++s) acc[s] = (f32x4){0.f, 0.f, 0.f, 0.f};

  int arow = tid >> 2, ak0 = (tid & 3) * 8;
  const float* asrc0 = x + ((size_t)arow * SEQ + t) * DIM + ak0;
  int brow = tid >> 1, bk0 = (tid & 1) * 16;
  const unsigned short* bsrc0 =
      WbT + ((size_t)(wsel * 512 + ncol0 + brow)) * 512 + bk0;

  for (int kk = 0; kk < 16; ++kk) {
    const float* asrc = asrc0 + kk * 32;
    float4 f0 = *(const float4*)(asrc);
    float4 f1 = *(const float4*)(asrc + 4);
    uint4 av;
    av.x = packbf(f0.x, f0.y);
    av.y = packbf(f0.z, f0.w);
    av.z = packbf(f1.x, f1.y);
    av.w = packbf(f1.z, f1.w);
    *(uint4*)(aS + arow * 40 + ak0) = av;
    const unsigned short* bsrc = bsrc0 + kk * 32;
    *(uint4*)(bS + brow * 40 + bk0)     = *(const uint4*)(bsrc);
    *(uint4*)(bS + brow * 40 + bk0 + 8) = *(const uint4*)(bsrc + 8);
    __syncthreads();

    s16x8 af = *(const s16x8*)(aS + (wv * 16 + lq) * 40 + quad * 8);
#pragma unroll
    for (int s = 0; s < 8; ++s) {
      s16x8 bf = *(const s16x8*)(bS + (s * 16 + lq) * 40 + quad * 8);
      acc[s] = __builtin_amdgcn_mfma_f32_16x16x32_bf16(af, bf, acc[s], 0, 0, 0);
    }
    __syncthreads();
  }

#pragma unroll
  for (int s = 0; s < 8; ++s) {
    int col = ncol0 + s * 16 + lq;
    float bv = bias[col];
#pragma unroll
    for (int v = 0; v < 4; ++v) {
      int b = wv * 16 + quad * 4 + v;
      pout[((size_t)(t * BATCH + b)) * DIM + col] = f2bf(acc[s][v] + bv);
    }
  }
}

// ---------------------------------------------------------------------------
// Kernel 3: base GEMM (prefix contribution via MFMA) — validated, unchanged.
// ---------------------------------------------------------------------------
template<int I>
__global__ __launch_bounds__(256) void base_gemm(
    const float* __restrict__ outp,
    const unsigned short* __restrict__ Bcat,
    unsigned short* __restrict__ baseO)
{
  constexpr int KI  = 4 * I;
  constexpr int K   = 128 * I;
  constexpr int NT  = I + 2;
  constexpr int NW  = NT * 128;
  constexpr int PER = 1 << I;

  __shared__ __align__(16) unsigned short aS[64 * 40];
  __shared__ __align__(16) unsigned short bS[128 * 40];

  int bx = blockIdx.x;
  int nt = bx % NT, n = bx / NT;
  int ncol0 = nt * 128;

  int tid = threadIdx.x;
  int wv = tid >> 6, lane = tid & 63;
  int lq = lane & 15, quad = lane >> 4;

  f32x4 acc[8];
#pragma unroll
  for (int s = 0; s < 8; ++s) acc[s] = (f32x4){0.f, 0.f, 0.f, 0.f};

  int arow = tid >> 2, ak0 = (tid & 3) * 8;
  const float* asrc0 = outp + ((size_t)arow * SEQ + (n * PER - 1)) * DIM + ak0;
  int brow = tid >> 1, bk0 = (tid & 1) * 16;
  const unsigned short* bsrc0 = Bcat + (size_t)(ncol0 + brow) * K + bk0;

  for (int kk = 0; kk < KI; ++kk) {
    uint4 av;
    if (n > 0) {
      const float* asrc = asrc0 + kk * 32;
      float4 f0 = *(const float4*)(asrc);
      float4 f1 = *(const float4*)(asrc + 4);
      av.x = packbf(f0.x, f0.y);
      av.y = packbf(f0.z, f0.w);
      av.z = packbf(f1.x, f1.y);
      av.w = packbf(f1.z, f1.w);
    } else {
      av = (uint4){0u, 0u, 0u, 0u};
    }
    *(uint4*)(aS + arow * 40 + ak0) = av;
    const unsigned short* bsrc = bsrc0 + kk * 32;
    *(uint4*)(bS + brow * 40 + bk0)     = *(const uint4*)(bsrc);
    *(uint4*)(bS + brow * 40 + bk0 + 8) = *(const uint4*)(bsrc + 8);
    __syncthreads();

    s16x8 af = *(const s16x8*)(aS + (wv * 16 + lq) * 40 + quad * 8);
#pragma unroll
    for (int s = 0; s < 8; ++s) {
      s16x8 bf = *(const s16x8*)(bS + (s * 16 + lq) * 40 + quad * 8);
      acc[s] = __builtin_amdgcn_mfma_f32_16x16x32_bf16(af, bf, acc[s], 0, 0, 0);
    }
    __syncthreads();
  }

#pragma unroll
  for (int s = 0; s < 8; ++s) {
    int col = ncol0 + s * 16 + lq;
#pragma unroll
    for (int v = 0; v < 4; ++v) {
      int bb = wv * 16 + quad * 4 + v;
      baseO[(size_t)(n * 64 + bb) * NW + col] = f2bf(acc[s][v]);
    }
  }
}

// ---------------------------------------------------------------------------
// Kernel 4: scan phase. 64 WGs (one batch row each), 2M threads.
// UN-STACKED roles — no thread holds more than ONE 64-reg weight array
// (the R3/R4 spill-serialization failure mode):
//   t <  M : R thread, wr[64]   (r-gate col t)
//   t >= M : H thread, wh[64]   (h-matmul k-slice ks=(t-M)>>7, col jh)
// Z weights live in LDS (32 KB); H slice-0 threads compute z in seg1 (idle
// there otherwise), z result stays in a register through finalize.
// Per update: seg1 (R-dot || z-dot) | barA | seg2 H-slice dots (partials for
// ks>0) | barB (I>0 only) | finalize on slice-0 | barC.  lgkm-only barriers.
// ---------------------------------------------------------------------------
template<int I>
__global__ __launch_bounds__(2 * (I + 1) * 128, 4)
void scan_phase(
    const unsigned short* __restrict__ px,
    const unsigned short* __restrict__ pr,
    const unsigned short* __restrict__ pz,
    const unsigned* __restrict__ crpk,   // [64][M]   own-rows of Cr, k-pair packed
    const unsigned* __restrict__ czpk,   // [64][128] own-rows of Cz
    const unsigned* __restrict__ chpk,   // [64*(I+1)][128] all rows of Ch
    const unsigned short* __restrict__ base,  // [U*64][NW], I>0
    float* __restrict__ out)
{
  constexpr int M   = (I + 1) * 128;
  constexpr int IN  = I * 128;
  constexpr int PER = 1 << I;
  constexpr int U   = 512 >> I;
  constexpr int NW  = M + 128;
  constexpr int NTH = 2 * M;

  __shared__ __align__(16) unsigned wzS[64 * 128];   // 32 KB
  __shared__ __align__(16) unsigned hPk[64];
  __shared__ __align__(16) unsigned uPk[M / 2];
  __shared__ float hS[128];
  __shared__ float part[(I > 0) ? I : 1][128];

  const int b = blockIdx.x;
  const int t = threadIdx.x;

  const bool isR = (t < M);
  const bool isH = (t >= M);
  const int  hidx = t - M;
  const int  ks = hidx >> 7;         // h k-slice 0..I (valid when isH)
  const int  jh = hidx & 127;
  const bool isF = isH && (ks == 0); // finalize + z owners

  // ---- z-weights -> LDS (cooperative, coalesced)
  for (int idx = t; idx < 64 * 128; idx += NTH) wzS[idx] = czpk[idx];

  // ---- weights -> pinned VGPRs (ONE 64-reg array per thread, never two)
  unsigned wr[64];
  if (isR) {
#pragma unroll
    for (int k = 0; k < 64; ++k) wr[k] = crpk[k * M + t];
    pinv(wr);
  }
  unsigned wh[64];
  if (isH) {
#pragma unroll
    for (int k = 0; k < 64; ++k) wh[k] = chpk[(ks * 64 + k) * 128 + jh];
    pinv(wh);
  }

  if (t < 128) hS[t] = 0.f;
  if (t < 64)  hPk[t] = 0u;
  bar_lds();

  // ---- initial operand loads (update n=0, s=0; prev(s=-1)=0)
  unsigned short prV = 0, pzV = 0, pxV = 0, bRV = 0, bZV = 0;
  float prevV = 0.f;
  {
    const size_t row0 = (size_t)b * DIM;
    if (isR) prV = pr[row0 + t];
    if (isF) { pzV = pz[row0 + IN + jh]; pxV = px[row0 + IN + jh]; }
    if constexpr (I > 0) {
      if (isR) bRV = base[(size_t)b * NW + t];
      if (isF) bZV = base[(size_t)b * NW + M + jh];
    }
  }

  for (int n = 0; n < U; ++n) {
    const int s = n * PER;

    // ---- prefetch next update's operands (fly across the lgkm barriers)
    unsigned short prN = 0, pzN = 0, pxN = 0, bRN = 0, bZN = 0;
    float prevN = 0.f;
    {
      const int n1 = (n + 1 < U) ? n + 1 : n;
      const int s1 = n1 * PER;
      const size_t row1 = ((size_t)s1 * BATCH + b) * DIM;
      if (isR) prN = pr[row1 + t];
      if (isF) { pzN = pz[row1 + IN + jh]; pxN = px[row1 + IN + jh]; }
      if constexpr (I > 0) {
        const size_t brow1 = (size_t)(n1 * 64 + b) * NW;
        if (isR) bRN = base[brow1 + t];
        if (isF) bZN = base[brow1 + M + jh];
        if (isR && t < IN)   // lower-block trajectory (written by earlier kernels)
          prevN = out[((size_t)b * SEQ + (s1 - 1)) * DIM + t];
      }
    }

    // ---------------- seg1: r-gate (R) || z-gate (H slice-0) ----------------
    if (isR) {
      float a0 = 0.f, a1 = 0.f;
      const uint2* hp2 = (const uint2*)hPk;
#pragma unroll
      for (int q = 0; q < 32; ++q) {
        uint2 h2 = hp2[q];
        a0 = dot2(wr[2 * q],     h2.x, a0);
        a1 = dot2(wr[2 * q + 1], h2.y, a1);
      }
      float ar = bf2f(prV) + a0 + a1;
      if constexpr (I > 0) ar += bf2f(bRV);
      float r = sigm(ar);
      float hp0;
      if constexpr (I == 0) hp0 = hS[t];
      else hp0 = (t >= IN) ? hS[t - IN] : prevV;
      float u = r * hp0;
      float uo = __shfl_xor(u, 1);
      if (!(t & 1)) uPk[t >> 1] = packbf(u, uo);
    }
    float zloc = 0.f;
    if (isF) {
      float a0 = 0.f, a1 = 0.f;
#pragma unroll
      for (int k = 0; k < 64; k += 2) {
        a0 = dot2(wzS[k * 128 + jh],       hPk[k],     a0);
        a1 = dot2(wzS[(k + 1) * 128 + jh], hPk[k + 1], a1);
      }
      float az = bf2f(pzV) + a0 + a1;
      if constexpr (I > 0) az += bf2f(bZV);
      zloc = sigm(az);
    }
    bar_lds();  // A: uPk ready

    // ---------------- seg2: h-matmul k-slices ----------------
    float ahOwn = 0.f;
    if (isH) {
      float a0 = 0.f, a1 = 0.f;
      const uint2* up2 = (const uint2*)(uPk + ks * 64);
#pragma unroll
      for (int q = 0; q < 32; ++q) {
        uint2 u2 = up2[q];
        a0 = dot2(wh[2 * q],     u2.x, a0);
        a1 = dot2(wh[2 * q + 1], u2.y, a1);
      }
      ahOwn = a0 + a1;
      if constexpr (I > 0) { if (ks > 0) part[ks - 1][jh] = ahOwn; }
    }
    if constexpr (I > 0) bar_lds();  // B: partials ready

    // ---------------- seg3: finalize (H slice-0) ----------------
    if (isF) {
      float tot = ahOwn + bf2f(pxV);
      if constexpr (I >= 1) tot += part[0][jh];
      if constexpr (I >= 2) tot += part[1][jh];
      if constexpr (I >= 3) tot += part[2][jh];
      float hnew = sigm(tot);
      float hold = hS[jh];
      float v = zloc * hnew + (1.f - zloc) * hold;
      hS[jh] = v;
      float vo = __shfl_xor(v, 1);
      if (!(jh & 1)) hPk[jh >> 1] = packbf(v, vo);
      float* orow = out + ((size_t)b * SEQ + s) * DIM + IN + jh;
#pragma unroll
      for (int p = 0; p < PER; ++p) orow[(size_t)p * DIM] = v;
    }
    bar_lds();  // C: hS/hPk ready for next update

    prV = prN; pzV = pzN; pxV = pxN; bRV = bRN; bZV = bZN; prevV = prevN;
  }
}

// ---------------------------------------------------------------------------
// Host launcher
// ---------------------------------------------------------------------------
extern "C" void kernel_launch(void* const* d_in, const int* in_sizes, int n_in,
                              void* d_out, int out_size, void* d_ws, size_t ws_size,
                              hipStream_t stream) {
  (void)in_sizes; (void)n_in; (void)out_size; (void)ws_size;

  const float* x  = (const float*)d_in[0];
  const float* W  = (const float*)d_in[1];
  const float* bb = (const float*)d_in[2];
  const float* Wr = (const float*)d_in[3];
  const float* br = (const float*)d_in[4];
  const float* Wz = (const float*)d_in[5];
  const float* bz = (const float*)d_in[6];
  const float* ch_[4]; const float* cr_[4]; const float* cz_[4];
  for (int i = 0; i < 4; ++i) {
    ch_[i] = (const float*)d_in[7 + 3 * i];
    cr_[i] = (const float*)d_in[8 + 3 * i];
    cz_[i] = (const float*)d_in[9 + 3 * i];
  }

  char* ws = (char*)d_ws;
  size_t off = 0;
  auto alloc = [&](size_t bytes) -> void* {
    void* p = ws + off;
    off += (bytes + 255) & ~(size_t)255;
    return p;
  };

  unsigned short* WbT = (unsigned short*)alloc(3ull * 512 * 512 * 2);
  unsigned* Crpk[4]; unsigned* Chpk[4]; unsigned* Czpk[4];
  unsigned short* Bcat[4] = {nullptr, nullptr, nullptr, nullptr};
  for (int i = 0; i < 4; ++i) {
    int m = (i + 1) * 128;
    Crpk[i] = (unsigned*)alloc((size_t)64 * m * 4);
    Chpk[i] = (unsigned*)alloc((size_t)(m / 2) * 128 * 4);
    Czpk[i] = (unsigned*)alloc((size_t)64 * 128 * 4);
  }
  for (int i = 1; i < 4; ++i) {
    int m = (i + 1) * 128, iN = i * 128;
    Bcat[i] = (unsigned short*)alloc((size_t)(m + 128) * iN * 2);
  }
  unsigned short* p0 = (unsigned short*)alloc((size_t)SEQ * BATCH * DIM * 2);
  unsigned short* p1 = (unsigned short*)alloc((size_t)SEQ * BATCH * DIM * 2);
  unsigned short* p2 = (unsigned short*)alloc((size_t)SEQ * BATCH * DIM * 2);
  unsigned short* baseB = (unsigned short*)alloc((size_t)16384 * 384 * 2);

  // ---- cast/pack jobs
  CastJobs jobs{};
  int jn = 0;
  const float* wsrc[3] = {W, Wr, Wz};
  for (int j = 0; j < 3; ++j) {
    jobs.src[jn] = wsrc[j]; jobs.dst[jn] = WbT + (size_t)j * 512 * 512;
    jobs.n[jn] = 512 * 512; jobs.mode[jn] = 1; jobs.m[jn] = 512; jobs.iN[jn] = 0; jn++;
  }
  for (int i = 0; i < 4; ++i) {
    int m = (i + 1) * 128, iN = i * 128;
    jobs.src[jn] = cr_[i]; jobs.dst[jn] = Crpk[i];
    jobs.n[jn] = 64 * m; jobs.mode[jn] = 3; jobs.m[jn] = m; jobs.iN[jn] = iN; jn++;
    jobs.src[jn] = ch_[i]; jobs.dst[jn] = Chpk[i];
    jobs.n[jn] = (m / 2) * 128; jobs.mode[jn] = 4; jobs.m[jn] = m; jobs.iN[jn] = iN; jn++;
    jobs.src[jn] = cz_[i]; jobs.dst[jn] = Czpk[i];
    jobs.n[jn] = 64 * 128; jobs.mode[jn] = 5; jobs.m[jn] = m; jobs.iN[jn] = iN; jn++;
  }
  for (int i = 1; i < 4; ++i) {
    int m = (i + 1) * 128, iN = i * 128;
    jobs.src[jn] = cr_[i]; jobs.src2[jn] = cz_[i]; jobs.dst[jn] = Bcat[i];
    jobs.n[jn] = (m + 128) * iN; jobs.mode[jn] = 6; jobs.m[jn] = m; jobs.iN[jn] = iN; jn++;
  }
  cast_kernel<<<256, 256, 0, stream>>>(jobs);

  // ---- projections
  proj_kernel<<<SEQ * 12, 256, 0, stream>>>(x, WbT, bb, br, bz, p0, p1, p2);

  float* outp = (float*)d_out;

  // ---- cascade: B0 -> G1 -> B1 -> G2 -> B2 -> G3 -> B3
  scan_phase<0><<<64, 256, 0, stream>>>(p0, p1, p2, Crpk[0], Czpk[0], Chpk[0],
                                        nullptr, outp);
  base_gemm<1><<<256 * 3, 256, 0, stream>>>(outp, Bcat[1], baseB);
  scan_phase<1><<<64, 512, 0, stream>>>(p0, p1, p2, Crpk[1], Czpk[1], Chpk[1],
                                        baseB, outp);
  base_gemm<2><<<128 * 4, 256, 0, stream>>>(outp, Bcat[2], baseB);
  scan_phase<2><<<64, 768, 0, stream>>>(p0, p1, p2, Crpk[2], Czpk[2], Chpk[2],
                                        baseB, outp);
  base_gemm<3><<<64 * 5, 256, 0, stream>>>(outp, Bcat[3], baseB);
  scan_phase<3><<<64, 1024, 0, stream>>>(p0, p1, p2, Crpk[3], Czpk[3], Chpk[3],
                                         baseB, outp);
}

// Round 6
// 2145.273 us; speedup vs baseline: 2.9206x; 2.9206x over previous
//
#include <hip/hip_runtime.h>

#define SEQ   512
#define BATCH 64
#define DIM   512

typedef float  f32x4 __attribute__((ext_vector_type(4)));
typedef short  s16x8 __attribute__((ext_vector_type(8)));
typedef __bf16 bf16x2 __attribute__((ext_vector_type(2)));

__device__ __forceinline__ float bits2f(unsigned u) {
  union { unsigned u; float f; } v; v.u = u; return v.f;
}
__device__ __forceinline__ float bf2f(unsigned short h) { return bits2f((unsigned)h << 16); }
__device__ __forceinline__ float bflo(unsigned u) { return bits2f(u << 16); }
__device__ __forceinline__ float bfhi(unsigned u) { return bits2f(u & 0xFFFF0000u); }
__device__ __forceinline__ unsigned short f2bf(float f) {
  union { float f; unsigned u; } v; v.f = f;
  unsigned r = v.u + 0x7FFFu + ((v.u >> 16) & 1u);
  return (unsigned short)(r >> 16);
}
__device__ __forceinline__ unsigned packbf(float lo, float hi) {
  return (unsigned)f2bf(lo) | ((unsigned)f2bf(hi) << 16);
}
__device__ __forceinline__ float sigm(float x) { return 1.0f / (1.0f + __expf(-x)); }

__device__ __forceinline__ float dot2(unsigned w, unsigned h, float acc) {
#if __has_builtin(__builtin_amdgcn_fdot2_f32_bf16)
  return __builtin_amdgcn_fdot2_f32_bf16(__builtin_bit_cast(bf16x2, w),
                                         __builtin_bit_cast(bf16x2, h), acc, false);
#else
  return acc + bflo(w) * bflo(h) + bfhi(w) * bfhi(h);
#endif
}

// Barrier draining ONLY LDS (lgkmcnt) — global prefetch loads / out-stores stay
// in flight. Safe: no intra-kernel global RAW (prev-trajectory cols are written
// only by EARLIER kernel launches).
__device__ __forceinline__ void bar_lds() {
  asm volatile("s_waitcnt lgkmcnt(0)\n\ts_barrier" ::: "memory");
}

template<int N>
__device__ __forceinline__ void pinv(unsigned (&w)[N]) {
#pragma unroll
  for (int k = 0; k < N; ++k) asm volatile("" : "+v"(w[k]));
}

// ---------------------------------------------------------------------------
// Kernel 1: cast/pack weights (validated R2-R5).
// ---------------------------------------------------------------------------
#define NJOBS 18
struct CastJobs {
  const float* src[NJOBS];
  const float* src2[NJOBS];
  void*        dst[NJOBS];
  int          n[NJOBS];
  int          mode[NJOBS];
  int          m[NJOBS];
  int          iN[NJOBS];
};

__global__ __launch_bounds__(256) void cast_kernel(CastJobs jobs) {
  int gsz = gridDim.x * blockDim.x;
  int gid = blockIdx.x * blockDim.x + threadIdx.x;
  for (int j = 0; j < NJOBS; ++j) {
    int n = jobs.n[j], mode = jobs.mode[j];
    int m = jobs.m[j], iN = jobs.iN[j];
    const float* s = jobs.src[j];
    if (mode == 1) {
      unsigned short* d = (unsigned short*)jobs.dst[j];
      for (int i = gid; i < n; i += gsz) {
        int k = i >> 9, nn = i & 511;
        d[nn * 512 + k] = f2bf(s[i]);
      }
    } else if (mode == 3) {
      unsigned* d = (unsigned*)jobs.dst[j];
      for (int i = gid; i < n; i += gsz) {
        int k2 = i / m, jj = i - k2 * m;
        d[i] = packbf(s[(iN + 2 * k2) * m + jj], s[(iN + 2 * k2 + 1) * m + jj]);
      }
    } else if (mode == 4) {
      unsigned* d = (unsigned*)jobs.dst[j];
      for (int i = gid; i < n; i += gsz) {
        int k2 = i >> 7, jj = i & 127;
        d[i] = packbf(s[(2 * k2) * 128 + jj], s[(2 * k2 + 1) * 128 + jj]);
      }
    } else if (mode == 5) {
      unsigned* d = (unsigned*)jobs.dst[j];
      for (int i = gid; i < n; i += gsz) {
        int k2 = i >> 7, jj = i & 127;
        d[i] = packbf(s[(iN + 2 * k2) * 128 + jj], s[(iN + 2 * k2 + 1) * 128 + jj]);
      }
    } else if (mode == 6) {
      const float* s2 = jobs.src2[j];
      unsigned short* d = (unsigned short*)jobs.dst[j];
      for (int i = gid; i < n; i += gsz) {
        int nrow = i / iN, k = i - nrow * iN;
        float v = (nrow < m) ? s[k * m + nrow] : s2[k * 128 + (nrow - m)];
        d[i] = f2bf(v);
      }
    }
  }
}

// ---------------------------------------------------------------------------
// Kernel 2: projection GEMM (bf16 MFMA) — validated, unchanged.
// ---------------------------------------------------------------------------
__global__ __launch_bounds__(256) void proj_kernel(
    const float* __restrict__ x,
    const unsigned short* __restrict__ WbT,
    const float* __restrict__ bias0, const float* __restrict__ bias1,
    const float* __restrict__ bias2,
    unsigned short* __restrict__ p0, unsigned short* __restrict__ p1,
    unsigned short* __restrict__ p2)
{
  __shared__ __align__(16) unsigned short aS[64 * 40];
  __shared__ __align__(16) unsigned short bS[128 * 40];

  int bx = blockIdx.x;
  int nt = bx % 12, t = bx / 12;
  int wsel = nt >> 2, ncol0 = (nt & 3) * 128;
  const float* bias = (wsel == 0) ? bias0 : (wsel == 1 ? bias1 : bias2);
  unsigned short* pout = (wsel == 0) ? p0 : (wsel == 1 ? p1 : p2);

  int tid = threadIdx.x;
  int wv = tid >> 6, lane = tid & 63;
  int lq = lane & 15, quad = lane >> 4;

  f32x4 acc[8];
#pragma unroll
  for (int s = 0; s < 8; ++s) acc[s] = (f32x4){0.f, 0.f, 0.f, 0.f};

  int arow = tid >> 2, ak0 = (tid & 3) * 8;
  const float* asrc0 = x + ((size_t)arow * SEQ + t) * DIM + ak0;
  int brow = tid >> 1, bk0 = (tid & 1) * 16;
  const unsigned short* bsrc0 =
      WbT + ((size_t)(wsel * 512 + ncol0 + brow)) * 512 + bk0;

  for (int kk = 0; kk < 16; ++kk) {
    const float* asrc = asrc0 + kk * 32;
    float4 f0 = *(const float4*)(asrc);
    float4 f1 = *(const float4*)(asrc + 4);
    uint4 av;
    av.x = packbf(f0.x, f0.y);
    av.y = packbf(f0.z, f0.w);
    av.z = packbf(f1.x, f1.y);
    av.w = packbf(f1.z, f1.w);
    *(uint4*)(aS + arow * 40 + ak0) = av;
    const unsigned short* bsrc = bsrc0 + kk * 32;
    *(uint4*)(bS + brow * 40 + bk0)     = *(const uint4*)(bsrc);
    *(uint4*)(bS + brow * 40 + bk0 + 8) = *(const uint4*)(bsrc + 8);
    __syncthreads();

    s16x8 af = *(const s16x8*)(aS + (wv * 16 + lq) * 40 + quad * 8);
#pragma unroll
    for (int s = 0; s < 8; ++s) {
      s16x8 bf = *(const s16x8*)(bS + (s * 16 + lq) * 40 + quad * 8);
      acc[s] = __builtin_amdgcn_mfma_f32_16x16x32_bf16(af, bf, acc[s], 0, 0, 0);
    }
    __syncthreads();
  }

#pragma unroll
  for (int s = 0; s < 8; ++s) {
    int col = ncol0 + s * 16 + lq;
    float bv = bias[col];
#pragma unroll
    for (int v = 0; v < 4; ++v) {
      int b = wv * 16 + quad * 4 + v;
      pout[((size_t)(t * BATCH + b)) * DIM + col] = f2bf(acc[s][v] + bv);
    }
  }
}

// ---------------------------------------------------------------------------
// Kernel 3: base GEMM (prefix contribution via MFMA) — validated, unchanged.
// ---------------------------------------------------------------------------
template<int I>
__global__ __launch_bounds__(256) void base_gemm(
    const float* __restrict__ outp,
    const unsigned short* __restrict__ Bcat,
    unsigned short* __restrict__ baseO)
{
  constexpr int KI  = 4 * I;
  constexpr int K   = 128 * I;
  constexpr int NT  = I + 2;
  constexpr int NW  = NT * 128;
  constexpr int PER = 1 << I;

  __shared__ __align__(16) unsigned short aS[64 * 40];
  __shared__ __align__(16) unsigned short bS[128 * 40];

  int bx = blockIdx.x;
  int nt = bx % NT, n = bx / NT;
  int ncol0 = nt * 128;

  int tid = threadIdx.x;
  int wv = tid >> 6, lane = tid & 63;
  int lq = lane & 15, quad = lane >> 4;

  f32x4 acc[8];
#pragma unroll
  for (int s = 0; s < 8; ++s) acc[s] = (f32x4){0.f, 0.f, 0.f, 0.f};

  int arow = tid >> 2, ak0 = (tid & 3) * 8;
  const float* asrc0 = outp + ((size_t)arow * SEQ + (n * PER - 1)) * DIM + ak0;
  int brow = tid >> 1, bk0 = (tid & 1) * 16;
  const unsigned short* bsrc0 = Bcat + (size_t)(ncol0 + brow) * K + bk0;

  for (int kk = 0; kk < KI; ++kk) {
    uint4 av;
    if (n > 0) {
      const float* asrc = asrc0 + kk * 32;
      float4 f0 = *(const float4*)(asrc);
      float4 f1 = *(const float4*)(asrc + 4);
      av.x = packbf(f0.x, f0.y);
      av.y = packbf(f0.z, f0.w);
      av.z = packbf(f1.x, f1.y);
      av.w = packbf(f1.z, f1.w);
    } else {
      av = (uint4){0u, 0u, 0u, 0u};
    }
    *(uint4*)(aS + arow * 40 + ak0) = av;
    const unsigned short* bsrc = bsrc0 + kk * 32;
    *(uint4*)(bS + brow * 40 + bk0)     = *(const uint4*)(bsrc);
    *(uint4*)(bS + brow * 40 + bk0 + 8) = *(const uint4*)(bsrc + 8);
    __syncthreads();

    s16x8 af = *(const s16x8*)(aS + (wv * 16 + lq) * 40 + quad * 8);
#pragma unroll
    for (int s = 0; s < 8; ++s) {
      s16x8 bf = *(const s16x8*)(bS + (s * 16 + lq) * 40 + quad * 8);
      acc[s] = __builtin_amdgcn_mfma_f32_16x16x32_bf16(af, bf, acc[s], 0, 0, 0);
    }
    __syncthreads();
  }

#pragma unroll
  for (int s = 0; s < 8; ++s) {
    int col = ncol0 + s * 16 + lq;
#pragma unroll
    for (int v = 0; v < 4; ++v) {
      int bb = wv * 16 + quad * 4 + v;
      baseO[(size_t)(n * 64 + bb) * NW + col] = f2bf(acc[s][v]);
    }
  }
}

// ---------------------------------------------------------------------------
// Kernel 4: scan phase. 64 WGs (one batch row each), 2M threads.
// KEY INVARIANT (R3/R4/R5 failures): each thread pins exactly ONE 64-reg
// weight array `w` — the SAME program variable for every role, loaded from a
// role-selected (pointer, stride). Static pressure ~100 regs < 128 cap
// (launch_bounds(NTH,4)) -> no spill, no remat.
//   t <  M : R thread — w = Cr column t        (r-gate, used in seg1)
//   t >= M : H thread — w = Ch k-slice ks col jh (h-matmul, used in seg2)
// Z weights in LDS (32 KB, conflict-free per R5 counters); H slice-0 threads
// compute z in seg1 (idle there otherwise), z stays in a register.
// ---------------------------------------------------------------------------
template<int I>
__global__ __launch_bounds__(2 * (I + 1) * 128, 4)
void scan_phase(
    const unsigned short* __restrict__ px,
    const unsigned short* __restrict__ pr,
    const unsigned short* __restrict__ pz,
    const unsigned* __restrict__ crpk,   // [64][M]   k-pair-packed Cr (own rows)
    const unsigned* __restrict__ czpk,   // [64][128] k-pair-packed Cz (own rows)
    const unsigned* __restrict__ chpk,   // [64*(I+1)][128] k-pair-packed Ch
    const unsigned short* __restrict__ base,  // [U*64][NW], I>0
    float* __restrict__ out)
{
  constexpr int M   = (I + 1) * 128;
  constexpr int IN  = I * 128;
  constexpr int PER = 1 << I;
  constexpr int U   = 512 >> I;
  constexpr int NW  = M + 128;
  constexpr int NTH = 2 * M;

  __shared__ __align__(16) unsigned wzS[64 * 128];   // 32 KB
  __shared__ __align__(16) unsigned hPk[64];
  __shared__ __align__(16) unsigned uPk[M / 2];
  __shared__ float hS[128];
  __shared__ float part[(I > 0) ? I : 1][128];

  const int b = blockIdx.x;
  const int t = threadIdx.x;

  const bool isR = (t < M);        // wave-uniform (M % 128 == 0)
  const bool isH = (t >= M);
  const int  hidx = t - M;
  const int  ks = hidx >> 7;       // h k-slice 0..I (valid when isH)
  const int  jh = hidx & 127;
  const bool isF = isH && (ks == 0); // finalize + z owners

  // ---- z-weights -> LDS (cooperative, coalesced)
  for (int idx = t; idx < 64 * 128; idx += NTH) wzS[idx] = czpk[idx];

  // ---- ONE pinned weight array per thread, role-selected source
  const unsigned* wsrc;
  int wstr;
  if (isR) { wsrc = crpk + t;                    wstr = M;   }
  else     { wsrc = chpk + (ks * 64) * 128 + jh; wstr = 128; }
  unsigned w[64];
#pragma unroll
  for (int k = 0; k < 64; ++k) w[k] = wsrc[(size_t)k * wstr];
  pinv(w);

  if (t < 128) hS[t] = 0.f;
  if (t < 64)  hPk[t] = 0u;
  bar_lds();

  // ---- initial operand loads (update n=0, s=0; prev(s=-1)=0)
  unsigned short prV = 0, pzV = 0, pxV = 0, bRV = 0, bZV = 0;
  float prevV = 0.f;
  {
    const size_t row0 = (size_t)b * DIM;
    if (isR) prV = pr[row0 + t];
    if (isF) { pzV = pz[row0 + IN + jh]; pxV = px[row0 + IN + jh]; }
    if constexpr (I > 0) {
      if (isR) bRV = base[(size_t)b * NW + t];
      if (isF) bZV = base[(size_t)b * NW + M + jh];
    }
  }

  for (int n = 0; n < U; ++n) {
    const int s = n * PER;

    // ---- prefetch next update's operands (fly across the lgkm barriers)
    unsigned short prN = 0, pzN = 0, pxN = 0, bRN = 0, bZN = 0;
    float prevN = 0.f;
    {
      const int n1 = (n + 1 < U) ? n + 1 : n;
      const int s1 = n1 * PER;
      const size_t row1 = ((size_t)s1 * BATCH + b) * DIM;
      if (isR) prN = pr[row1 + t];
      if (isF) { pzN = pz[row1 + IN + jh]; pxN = px[row1 + IN + jh]; }
      if constexpr (I > 0) {
        const size_t brow1 = (size_t)(n1 * 64 + b) * NW;
        if (isR) bRN = base[brow1 + t];
        if (isF) bZN = base[brow1 + M + jh];
        if (isR && t < IN)   // lower-block trajectory (written by earlier kernels)
          prevN = out[((size_t)b * SEQ + (s1 - 1)) * DIM + t];
      }
    }

    // ---------------- seg1: r-gate (R) || z-gate (H slice-0) ----------------
    if (isR) {
      float a0 = 0.f, a1 = 0.f;
      const uint4* hp4 = (const uint4*)hPk;
#pragma unroll
      for (int q = 0; q < 16; ++q) {
        uint4 h4 = hp4[q];
        a0 = dot2(w[4 * q],     h4.x, a0);
        a1 = dot2(w[4 * q + 1], h4.y, a1);
        a0 = dot2(w[4 * q + 2], h4.z, a0);
        a1 = dot2(w[4 * q + 3], h4.w, a1);
      }
      float ar = bf2f(prV) + a0 + a1;
      if constexpr (I > 0) ar += bf2f(bRV);
      float r = sigm(ar);
      float hp0;
      if constexpr (I == 0) hp0 = hS[t];
      else hp0 = (t >= IN) ? hS[t - IN] : prevV;
      float u = r * hp0;
      float uo = __shfl_xor(u, 1);
      if (!(t & 1)) uPk[t >> 1] = packbf(u, uo);
    }
    float zloc = 0.f;
    if (isF) {
      float a0 = 0.f, a1 = 0.f;
#pragma unroll
      for (int k = 0; k < 64; k += 2) {
        a0 = dot2(wzS[k * 128 + jh],       hPk[k],     a0);
        a1 = dot2(wzS[(k + 1) * 128 + jh], hPk[k + 1], a1);
      }
      float az = bf2f(pzV) + a0 + a1;
      if constexpr (I > 0) az += bf2f(bZV);
      zloc = sigm(az);
    }
    bar_lds();  // A: uPk ready

    // ---------------- seg2: h-matmul k-slices (H threads use w) -------------
    float ahOwn = 0.f;
    if (isH) {
      float a0 = 0.f, a1 = 0.f;
      const uint4* up4 = (const uint4*)(uPk + ks * 64);
#pragma unroll
      for (int q = 0; q < 16; ++q) {
        uint4 u4 = up4[q];
        a0 = dot2(w[4 * q],     u4.x, a0);
        a1 = dot2(w[4 * q + 1], u4.y, a1);
        a0 = dot2(w[4 * q + 2], u4.z, a0);
        a1 = dot2(w[4 * q + 3], u4.w, a1);
      }
      ahOwn = a0 + a1;
      if constexpr (I > 0) { if (ks > 0) part[ks - 1][jh] = ahOwn; }
    }
    if constexpr (I > 0) bar_lds();  // B: partials ready

    // ---------------- seg3: finalize (H slice-0) ----------------
    if (isF) {
      float tot = ahOwn + bf2f(pxV);
      if constexpr (I >= 1) tot += part[0][jh];
      if constexpr (I >= 2) tot += part[1][jh];
      if constexpr (I >= 3) tot += part[2][jh];
      float hnew = sigm(tot);
      float hold = hS[jh];
      float v = zloc * hnew + (1.f - zloc) * hold;
      hS[jh] = v;
      float vo = __shfl_xor(v, 1);
      if (!(jh & 1)) hPk[jh >> 1] = packbf(v, vo);
      float* orow = out + ((size_t)b * SEQ + s) * DIM + IN + jh;
#pragma unroll
      for (int p = 0; p < PER; ++p) orow[(size_t)p * DIM] = v;
    }
    bar_lds();  // C: hS/hPk ready for next update

    prV = prN; pzV = pzN; pxV = pxN; bRV = bRN; bZV = bZN; prevV = prevN;
  }
}

// ---------------------------------------------------------------------------
// Host launcher
// ---------------------------------------------------------------------------
extern "C" void kernel_launch(void* const* d_in, const int* in_sizes, int n_in,
                              void* d_out, int out_size, void* d_ws, size_t ws_size,
                              hipStream_t stream) {
  (void)in_sizes; (void)n_in; (void)out_size; (void)ws_size;

  const float* x  = (const float*)d_in[0];
  const float* W  = (const float*)d_in[1];
  const float* bb = (const float*)d_in[2];
  const float* Wr = (const float*)d_in[3];
  const float* br = (const float*)d_in[4];
  const float* Wz = (const float*)d_in[5];
  const float* bz = (const float*)d_in[6];
  const float* ch_[4]; const float* cr_[4]; const float* cz_[4];
  for (int i = 0; i < 4; ++i) {
    ch_[i] = (const float*)d_in[7 + 3 * i];
    cr_[i] = (const float*)d_in[8 + 3 * i];
    cz_[i] = (const float*)d_in[9 + 3 * i];
  }

  char* ws = (char*)d_ws;
  size_t off = 0;
  auto alloc = [&](size_t bytes) -> void* {
    void* p = ws + off;
    off += (bytes + 255) & ~(size_t)255;
    return p;
  };

  unsigned short* WbT = (unsigned short*)alloc(3ull * 512 * 512 * 2);
  unsigned* Crpk[4]; unsigned* Chpk[4]; unsigned* Czpk[4];
  unsigned short* Bcat[4] = {nullptr, nullptr, nullptr, nullptr};
  for (int i = 0; i < 4; ++i) {
    int m = (i + 1) * 128;
    Crpk[i] = (unsigned*)alloc((size_t)64 * m * 4);
    Chpk[i] = (unsigned*)alloc((size_t)(m / 2) * 128 * 4);
    Czpk[i] = (unsigned*)alloc((size_t)64 * 128 * 4);
  }
  for (int i = 1; i < 4; ++i) {
    int m = (i + 1) * 128, iN = i * 128;
    Bcat[i] = (unsigned short*)alloc((size_t)(m + 128) * iN * 2);
  }
  unsigned short* p0 = (unsigned short*)alloc((size_t)SEQ * BATCH * DIM * 2);
  unsigned short* p1 = (unsigned short*)alloc((size_t)SEQ * BATCH * DIM * 2);
  unsigned short* p2 = (unsigned short*)alloc((size_t)SEQ * BATCH * DIM * 2);
  unsigned short* baseB = (unsigned short*)alloc((size_t)16384 * 384 * 2);

  // ---- cast/pack jobs
  CastJobs jobs{};
  int jn = 0;
  const float* wsrc[3] = {W, Wr, Wz};
  for (int j = 0; j < 3; ++j) {
    jobs.src[jn] = wsrc[j]; jobs.dst[jn] = WbT + (size_t)j * 512 * 512;
    jobs.n[jn] = 512 * 512; jobs.mode[jn] = 1; jobs.m[jn] = 512; jobs.iN[jn] = 0; jn++;
  }
  for (int i = 0; i < 4; ++i) {
    int m = (i + 1) * 128, iN = i * 128;
    jobs.src[jn] = cr_[i]; jobs.dst[jn] = Crpk[i];
    jobs.n[jn] = 64 * m; jobs.mode[jn] = 3; jobs.m[jn] = m; jobs.iN[jn] = iN; jn++;
    jobs.src[jn] = ch_[i]; jobs.dst[jn] = Chpk[i];
    jobs.n[jn] = (m / 2) * 128; jobs.mode[jn] = 4; jobs.m[jn] = m; jobs.iN[jn] = iN; jn++;
    jobs.src[jn] = cz_[i]; jobs.dst[jn] = Czpk[i];
    jobs.n[jn] = 64 * 128; jobs.mode[jn] = 5; jobs.m[jn] = m; jobs.iN[jn] = iN; jn++;
  }
  for (int i = 1; i < 4; ++i) {
    int m = (i + 1) * 128, iN = i * 128;
    jobs.src[jn] = cr_[i]; jobs.src2[jn] = cz_[i]; jobs.dst[jn] = Bcat[i];
    jobs.n[jn] = (m + 128) * iN; jobs.mode[jn] = 6; jobs.m[jn] = m; jobs.iN[jn] = iN; jn++;
  }
  cast_kernel<<<256, 256, 0, stream>>>(jobs);

  // ---- projections
  proj_kernel<<<SEQ * 12, 256, 0, stream>>>(x, WbT, bb, br, bz, p0, p1, p2);

  float* outp = (float*)d_out;

  // ---- cascade: B0 -> G1 -> B1 -> G2 -> B2 -> G3 -> B3
  scan_phase<0><<<64, 256, 0, stream>>>(p0, p1, p2, Crpk[0], Czpk[0], Chpk[0],
                                        nullptr, outp);
  base_gemm<1><<<256 * 3, 256, 0, stream>>>(outp, Bcat[1], baseB);
  scan_phase<1><<<64, 512, 0, stream>>>(p0, p1, p2, Crpk[1], Czpk[1], Chpk[1],
                                        baseB, outp);
  base_gemm<2><<<128 * 4, 256, 0, stream>>>(outp, Bcat[2], baseB);
  scan_phase<2><<<64, 768, 0, stream>>>(p0, p1, p2, Crpk[2], Czpk[2], Chpk[2],
                                        baseB, outp);
  base_gemm<3><<<64 * 5, 256, 0, stream>>>(outp, Bcat[3], baseB);
  scan_phase<3><<<64, 1024, 0, stream>>>(p0, p1, p2, Crpk[3], Czpk[3], Chpk[3],
                                         baseB, outp);
}